// Round 1
// baseline (189.103 us; speedup 1.0000x reference)
//
#include <hip/hip_runtime.h>

// DenseFeatureNumericEmbedding: out[b, f*16+e] = sum_h relu(x[b,f]*W1[f,h]+b1[f,h])*W2[f,e,h] + b2[f,e]
// Piecewise-linear-in-x reformulation: per (f,e), the map x -> emb is piecewise linear
// with breakpoints t_h = -b1/W1. Precompute slope/intercept tables per (f, interval, e),
// then the main kernel is: binary-search interval + 16 FMA + 64B store per (b,f).

#define F_   128
#define H_   64
#define E_   16
#define NROW 65            // intervals 0..64
#define GRS  32            // global table row stride (16 S + 16 T floats)
#define RS   36            // LDS padded row stride (breaks bank alignment of k*32)
#define TPF  (NROW * RS)   // 2340 floats per feature in LDS
#define FPB  4             // features per block
#define BPB  512           // batch rows per block
#define THREADS 256

// ---------------- build kernel: one wave per feature ----------------
__global__ __launch_bounds__(64) void build_tables(
    const float* __restrict__ W1, const float* __restrict__ B1,
    const float* __restrict__ W2, const float* __restrict__ B2,
    float* __restrict__ tbl, float* __restrict__ bps)
{
    const int f = blockIdx.x;   // 0..127
    const int h = threadIdx.x;  // 0..63

    __shared__ float ts_raw[H_];
    __shared__ float ts_sorted[H_];
    __shared__ float scS[H_];
    __shared__ float scT[H_];

    const float w1 = W1[f * H_ + h];
    const float bb = B1[f * H_ + h];
    const bool  slope = (w1 != 0.0f);
    const float t   = slope ? (-bb / w1) : __builtin_inff();
    const float sgn = slope ? (w1 > 0.0f ? 1.0f : -1.0f) : 0.0f;
    // active as x -> -inf: W1<0 terms (x*W1 -> +inf), plus constant-on terms (W1==0, b1>0)
    const bool act0 = (w1 < 0.0f) || (!slope && bb > 0.0f);

    ts_raw[h] = t;
    __syncthreads();
    int rank = 0;
    #pragma unroll
    for (int j = 0; j < H_; ++j) {
        float tj = ts_raw[j];
        rank += (tj < t || (tj == t && j < h)) ? 1 : 0;  // tie-break by index -> permutation
    }
    ts_sorted[rank] = t;
    __syncthreads();
    bps[f * H_ + h] = ts_sorted[h];

    for (int e = 0; e < E_; ++e) {
        const float w2 = W2[(f * E_ + e) * H_ + h];
        // crossing t_h upward: W1>0 -> term turns ON (+), W1<0 -> OFF (-)
        const float dS = sgn * w1 * w2;
        const float dT = sgn * bb * w2;
        float bS = act0 ? w1 * w2 : 0.0f;
        float bT = act0 ? bb * w2 : 0.0f;
        #pragma unroll
        for (int d = 32; d; d >>= 1) { bS += __shfl_xor(bS, d); bT += __shfl_xor(bT, d); }

        __syncthreads();                 // protect scS/scT reuse across e
        scS[rank] = dS; scT[rank] = dT;  // scatter deltas into sorted order
        __syncthreads();
        float vS = scS[h], vT = scT[h];
        #pragma unroll
        for (int d = 1; d < 64; d <<= 1) {   // inclusive scan over sorted positions
            float uS = __shfl_up(vS, (unsigned)d);
            float uT = __shfl_up(vT, (unsigned)d);
            if (h >= d) { vS += uS; vT += uT; }
        }
        const float b2v = B2[f * E_ + e];
        float* row = tbl + ((size_t)f * NROW + (h + 1)) * GRS;  // interval k = h+1
        row[e]      = bS + vS;
        row[E_ + e] = bT + vT + b2v;
        if (h == 0) {
            float* r0 = tbl + (size_t)f * NROW * GRS;           // interval 0
            r0[e]      = bS;
            r0[E_ + e] = bT + b2v;
        }
    }
}

// ---------------- main kernel: 4 features x 512 batch rows per block ----------------
__global__ __launch_bounds__(THREADS) void embed_main(
    const float* __restrict__ x, const float* __restrict__ tbl,
    const float* __restrict__ bps, float* __restrict__ out)
{
    __shared__ float lt[FPB * TPF];   // 37440 B padded tables
    __shared__ float lb[FPB * H_];    // 1024 B sorted breakpoints

    const int tid = threadIdx.x;
    const int f0  = blockIdx.y * FPB;

    // stage tables (repack GRS=32 -> RS=36), float4 granules
    for (int i = tid; i < FPB * NROW * 8; i += THREADS) {
        int fl = i / (NROW * 8); int r = i - fl * (NROW * 8);
        int k = r >> 3; int c4 = (r & 7) << 2;
        float4 v = *(const float4*)(tbl + ((size_t)(f0 + fl) * NROW + k) * GRS + c4);
        *(float4*)(lt + fl * TPF + k * RS + c4) = v;
    }
    for (int i = tid; i < FPB * H_ / 4; i += THREADS) {
        int fl = i >> 4; int c4 = (i & 15) << 2;
        *(float4*)(lb + fl * H_ + c4) = *(const float4*)(bps + (size_t)(f0 + fl) * H_ + c4);
    }
    __syncthreads();

    const int   fl   = tid & (FPB - 1);
    const int   bloc = tid >> 2;
    const int   f    = f0 + fl;
    const float* myb = lb + fl * H_;
    const float* myt = lt + fl * TPF;
    const int bbase  = blockIdx.x * BPB;

    // prefetch x column values (gather, L3-backed)
    float xs[BPB / 64];
    #pragma unroll
    for (int it = 0; it < BPB / 64; ++it)
        xs[it] = x[(size_t)(bbase + it * 64 + bloc) * F_ + f];

    #pragma unroll
    for (int it = 0; it < BPB / 64; ++it) {
        const int   b  = bbase + it * 64 + bloc;
        const float xv = xs[it];
        // k = #{ sorted breakpoints <= xv } in [0,64]; branchless uniform search
        int k = 0;
        #pragma unroll
        for (int s = 64; s >= 1; s >>= 1) {
            int nk  = k + s;
            int idx = (nk <= 64) ? (nk - 1) : 63;   // clamp keeps LDS read in-bounds
            bool ok = (nk <= 64) && (myb[idx] <= xv);
            if (ok) k = nk;
        }
        const float* row = myt + k * RS;
        float4 s0 = *(const float4*)(row + 0);
        float4 s1 = *(const float4*)(row + 4);
        float4 s2 = *(const float4*)(row + 8);
        float4 s3 = *(const float4*)(row + 12);
        float4 t0 = *(const float4*)(row + 16);
        float4 t1 = *(const float4*)(row + 20);
        float4 t2 = *(const float4*)(row + 24);
        float4 t3 = *(const float4*)(row + 28);
        float4 o0, o1, o2, o3;
        o0.x = fmaf(s0.x, xv, t0.x); o0.y = fmaf(s0.y, xv, t0.y);
        o0.z = fmaf(s0.z, xv, t0.z); o0.w = fmaf(s0.w, xv, t0.w);
        o1.x = fmaf(s1.x, xv, t1.x); o1.y = fmaf(s1.y, xv, t1.y);
        o1.z = fmaf(s1.z, xv, t1.z); o1.w = fmaf(s1.w, xv, t1.w);
        o2.x = fmaf(s2.x, xv, t2.x); o2.y = fmaf(s2.y, xv, t2.y);
        o2.z = fmaf(s2.z, xv, t2.z); o2.w = fmaf(s2.w, xv, t2.w);
        o3.x = fmaf(s3.x, xv, t3.x); o3.y = fmaf(s3.y, xv, t3.y);
        o3.z = fmaf(s3.z, xv, t3.z); o3.w = fmaf(s3.w, xv, t3.w);
        float4* op = (float4*)(out + (size_t)b * (F_ * E_) + f * E_);
        op[0] = o0; op[1] = o1; op[2] = o2; op[3] = o3;
    }
}

extern "C" void kernel_launch(void* const* d_in, const int* in_sizes, int n_in,
                              void* d_out, int out_size, void* d_ws, size_t ws_size,
                              hipStream_t stream) {
    const float* x  = (const float*)d_in[0];
    const float* W1 = (const float*)d_in[1];
    const float* b1 = (const float*)d_in[2];
    const float* W2 = (const float*)d_in[3];
    const float* b2 = (const float*)d_in[4];
    float* out = (float*)d_out;
    const int B = in_sizes[0] / F_;     // 16384

    // workspace: table 128*65*32 floats (1.02 MB) + sorted breakpoints 128*64 floats (32 KB)
    float* tbl = (float*)d_ws;
    float* bps = tbl + (size_t)F_ * NROW * GRS;

    build_tables<<<F_, 64, 0, stream>>>(W1, b1, W2, b2, tbl, bps);
    dim3 grid(B / BPB, F_ / FPB);       // (32, 32) = 1024 blocks, 4 blocks/CU at 38.5 KB LDS
    embed_main<<<grid, THREADS, 0, stream>>>(x, tbl, bps, out);
}

// Round 3
// 182.754 us; speedup vs baseline: 1.0347x; 1.0347x over previous
//
#include <hip/hip_runtime.h>

// DenseFeatureNumericEmbedding: out[b, f*16+e] = sum_h relu(x[b,f]*W1[f,h]+b1[f,h])*W2[f,e,h] + b2[f,e]
// Piecewise-linear-in-x reformulation: per (f,e), the map x -> emb is piecewise linear
// with breakpoints t_h = -b1/W1. Precompute slope/intercept tables per (f, interval, e),
// then the main kernel is: binary-search interval + 4 FMA + one coalesced 16B store per thread.
//
// R1 change: lane remap (eq,fl,row) so each global_store_dwordx4 covers 16 rows x 256B
// CONTIGUOUS segments (full 128B lines), vs 64 scattered 16B segments before. Stores
// are nontemporal (134MB write-once stream).
// R2 fix: nontemporal store needs a native ext_vector_type, not HIP_vector_type.

#define F_   128
#define H_   64
#define E_   16
#define NROW 65            // intervals 0..64
#define GRS  32            // global table row stride (16 S + 16 T floats)
#define RS   36            // LDS padded row stride (16B-aligned, breaks k*32 bank alignment)
#define TPF  (NROW * RS)   // 2340 floats per feature in LDS
#define FPB  4             // features per block
#define RPI  16            // batch rows per iteration (256 threads / 16 lanes-per-row)
#define ITERS 8
#define BPB  (RPI * ITERS) // 128 batch rows per block
#define THREADS 256

typedef float vf4 __attribute__((ext_vector_type(4)));   // native vector for nt-store

// ---------------- build kernel: one wave per feature ----------------
__global__ __launch_bounds__(64) void build_tables(
    const float* __restrict__ W1, const float* __restrict__ B1,
    const float* __restrict__ W2, const float* __restrict__ B2,
    float* __restrict__ tbl, float* __restrict__ bps)
{
    const int f = blockIdx.x;   // 0..127
    const int h = threadIdx.x;  // 0..63

    __shared__ float ts_raw[H_];
    __shared__ float ts_sorted[H_];
    __shared__ float scS[H_];
    __shared__ float scT[H_];

    const float w1 = W1[f * H_ + h];
    const float bb = B1[f * H_ + h];
    const bool  slope = (w1 != 0.0f);
    const float t   = slope ? (-bb / w1) : __builtin_inff();
    const float sgn = slope ? (w1 > 0.0f ? 1.0f : -1.0f) : 0.0f;
    // active as x -> -inf: W1<0 terms (x*W1 -> +inf), plus constant-on terms (W1==0, b1>0)
    const bool act0 = (w1 < 0.0f) || (!slope && bb > 0.0f);

    ts_raw[h] = t;
    __syncthreads();
    int rank = 0;
    #pragma unroll
    for (int j = 0; j < H_; ++j) {
        float tj = ts_raw[j];
        rank += (tj < t || (tj == t && j < h)) ? 1 : 0;  // tie-break by index -> permutation
    }
    ts_sorted[rank] = t;
    __syncthreads();
    bps[f * H_ + h] = ts_sorted[h];

    for (int e = 0; e < E_; ++e) {
        const float w2 = W2[(f * E_ + e) * H_ + h];
        // crossing t_h upward: W1>0 -> term turns ON (+), W1<0 -> OFF (-)
        const float dS = sgn * w1 * w2;
        const float dT = sgn * bb * w2;
        float bS = act0 ? w1 * w2 : 0.0f;
        float bT = act0 ? bb * w2 : 0.0f;
        #pragma unroll
        for (int d = 32; d; d >>= 1) { bS += __shfl_xor(bS, d); bT += __shfl_xor(bT, d); }

        __syncthreads();                 // protect scS/scT reuse across e
        scS[rank] = dS; scT[rank] = dT;  // scatter deltas into sorted order
        __syncthreads();
        float vS = scS[h], vT = scT[h];
        #pragma unroll
        for (int d = 1; d < 64; d <<= 1) {   // inclusive scan over sorted positions
            float uS = __shfl_up(vS, (unsigned)d);
            float uT = __shfl_up(vT, (unsigned)d);
            if (h >= d) { vS += uS; vT += uT; }
        }
        const float b2v = B2[f * E_ + e];
        float* row = tbl + ((size_t)f * NROW + (h + 1)) * GRS;  // interval k = h+1
        row[e]      = bS + vS;
        row[E_ + e] = bT + vT + b2v;
        if (h == 0) {
            float* r0 = tbl + (size_t)f * NROW * GRS;           // interval 0
            r0[e]      = bS;
            r0[E_ + e] = bT + b2v;
        }
    }
}

// ---------------- main kernel ----------------
// lane map: eq = tid&3 (e-quartet), fl = (tid>>2)&3 (feature of 4), rloc = tid>>4 (0..15)
// store addr = out + b*2048 + (f0+fl)*16 + eq*4  -> lanes 0..15 cover 256B contiguous.
__global__ __launch_bounds__(THREADS) void embed_main(
    const float* __restrict__ x, const float* __restrict__ tbl,
    const float* __restrict__ bps, float* __restrict__ out)
{
    __shared__ float lt[FPB * TPF];   // 37440 B padded tables
    __shared__ float lb[FPB * H_];    // 1024 B sorted breakpoints

    const int tid = threadIdx.x;
    const int f0  = blockIdx.y * FPB;

    // stage tables (repack GRS=32 -> RS=36), float4 granules
    for (int i = tid; i < FPB * NROW * 8; i += THREADS) {
        int fl = i / (NROW * 8); int r = i - fl * (NROW * 8);
        int k = r >> 3; int c4 = (r & 7) << 2;
        float4 v = *(const float4*)(tbl + ((size_t)(f0 + fl) * NROW + k) * GRS + c4);
        *(float4*)(lt + fl * TPF + k * RS + c4) = v;
    }
    for (int i = tid; i < FPB * H_ / 4; i += THREADS) {
        int fl = i >> 4; int c4 = (i & 15) << 2;
        *(float4*)(lb + fl * H_ + c4) = *(const float4*)(bps + (size_t)(f0 + fl) * H_ + c4);
    }
    __syncthreads();

    const int   eq   = tid & 3;
    const int   fl   = (tid >> 2) & 3;
    const int   rloc = tid >> 4;          // 0..15
    const int   f    = f0 + fl;
    const float* myb = lb + fl * H_;
    const float* myt = lt + fl * TPF;
    const int bbase  = blockIdx.x * BPB;

    // prefetch x column values (gather; eq-lanes share the address -> broadcast)
    float xs[ITERS];
    #pragma unroll
    for (int it = 0; it < ITERS; ++it)
        xs[it] = x[(size_t)(bbase + it * RPI + rloc) * F_ + f];

    #pragma unroll
    for (int it = 0; it < ITERS; ++it) {
        const int   b  = bbase + it * RPI + rloc;
        const float xv = xs[it];
        // k = #{ sorted breakpoints <= xv } in [0,64]; branchless uniform search
        int k = 0;
        #pragma unroll
        for (int s = 64; s >= 1; s >>= 1) {
            int nk  = k + s;
            int idx = (nk <= 64) ? (nk - 1) : 63;   // clamp keeps LDS read in-bounds
            bool ok = (nk <= 64) && (myb[idx] <= xv);
            if (ok) k = nk;
        }
        const float* row = myt + k * RS + eq * 4;
        float4 S = *(const float4*)(row);
        float4 T = *(const float4*)(row + E_);
        vf4 o;
        o.x = fmaf(S.x, xv, T.x);
        o.y = fmaf(S.y, xv, T.y);
        o.z = fmaf(S.z, xv, T.z);
        o.w = fmaf(S.w, xv, T.w);
        vf4* op = (vf4*)(out + (size_t)b * (F_ * E_) + f * E_ + eq * 4);
        __builtin_nontemporal_store(o, op);
    }
}

extern "C" void kernel_launch(void* const* d_in, const int* in_sizes, int n_in,
                              void* d_out, int out_size, void* d_ws, size_t ws_size,
                              hipStream_t stream) {
    const float* x  = (const float*)d_in[0];
    const float* W1 = (const float*)d_in[1];
    const float* b1 = (const float*)d_in[2];
    const float* W2 = (const float*)d_in[3];
    const float* b2 = (const float*)d_in[4];
    float* out = (float*)d_out;
    const int B = in_sizes[0] / F_;     // 16384

    // workspace: table 128*65*32 floats (1.02 MB) + sorted breakpoints 128*64 floats (32 KB)
    float* tbl = (float*)d_ws;
    float* bps = tbl + (size_t)F_ * NROW * GRS;

    build_tables<<<F_, 64, 0, stream>>>(W1, b1, W2, b2, tbl, bps);
    dim3 grid(B / BPB, F_ / FPB);       // (128, 32) = 4096 blocks, 4 blocks/CU resident (38.5KB LDS)
    embed_main<<<grid, THREADS, 0, stream>>>(x, tbl, bps, out);
}